// Round 6
// baseline (175.414 us; speedup 1.0000x reference)
//
#include <hip/hip_runtime.h>

typedef unsigned short u16;
typedef __attribute__((ext_vector_type(8))) short frag8;   // 8 bf16 (4 VGPRs)
typedef __attribute__((ext_vector_type(4))) float f32x4;   // MFMA accumulator

__device__ __forceinline__ u16 f2bf(float f) {
  unsigned u; __builtin_memcpy(&u, &f, 4);
  u = (u + 0x7FFFu + ((u >> 16) & 1u)) >> 16;   // RNE (== v_cvt_pk_bf16_f32)
  return (u16)u;
}

// ---------------------------------------------------------------------------
// Round-12: pixel path -> global_load_lds chunk pipeline with counted vmcnt.
// Evidence: R5 (P[48] register-resident loads) was neutral -- the 256-VGPR cap
// forces the compiler to re-serialize register loads (VGPR_Count=88 across
// rounds proves it schedules for min pressure). Deep MLP therefore cannot
// come from VGPR-resident loads. global_load_lds is the zero-VGPR DMA path:
// outstanding loads bounded by the vmcnt queue, not registers (T3/T4).
//   - chunk = one patch-row of the tile: 3 ch x 512 f32 = 6 KB, linear in LDS
//   - double buffer; issue chunk i+2 after consuming chunk i; wait vmcnt(6)
//     (chunk i landed, i+1 in flight) -- never drain to 0 mid-loop
//   - counted waits are asm with "memory" clobber; ALL other vmem (weights,
//     b1, b2) is textually after the final vmcnt(0) so nothing pollutes the
//     count (loads cannot hoist across a memory-clobber asm)
//   - MLP: ping-pong register prefetch of next-kc weight frags (static idx)
// Arithmetic order identical to R4/R5 -> absmax expected unchanged (0.015625).
// LDS 18432 B/block -> 8 blocks/CU (147 KB); 8 waves/CU, each with 6-12 KB
// outstanding >> 9 KB/CU Little's-law target -> pixel stream at BW limit.
// ---------------------------------------------------------------------------

#define PIXA_OFF  0        // 6144 B  chunk buf A: [3 ch][512 f32]
#define PIXB_OFF  6144     // 6144 B  chunk buf B
#define FEATW_OFF 12288    // 2048 B  [64 p][16 coeff] bf16
#define HW_OFF    14336    // 4096 B  [64 p][32 n] bf16, XOR-swizzled
#define SMEM_BYTES 18432

#define WAITVM(n) asm volatile("s_waitcnt vmcnt(" #n ")" ::: "memory")

__global__ __launch_bounds__(256)
void prep_weights(const float* __restrict__ W1, const float* __restrict__ W2,
                  u16* __restrict__ wf) {
  const int g    = blockIdx.x * 256 + threadIdx.x;   // 0..3071
  const int quad = (g >> 4) & 3;
  const int l16  = g & 15;
  frag8 f;
  if (g < 1024) {
    // w1f[nt][lane]: A-frag of W1^T, f[j] = W1[k=quad*8+j][nt*16+l16], k>=16 -> 0
    const int nt = g >> 6;
    #pragma unroll
    for (int j = 0; j < 8; ++j) {
      const int k = quad * 8 + j;
      f[j] = (k < 16) ? (short)f2bf(W1[k * 256 + nt * 16 + l16]) : (short)0;
    }
    *(frag8*)(wf + (size_t)g * 8) = f;
  } else {
    // w2f[kc*4+et][lane]: B-frag, f[j] = W2[kc*32+quad*8+j][et*16+l16]
    const int idx = g - 1024;                        // 0..2047
    const int kc  = idx >> 8;
    const int et  = (idx >> 6) & 3;
    #pragma unroll
    for (int j = 0; j < 8; ++j)
      f[j] = (short)f2bf(W2[(kc * 32 + quad * 8 + j) * 64 + et * 16 + l16]);
    *(frag8*)(wf + 8192 + (size_t)idx * 8) = f;
  }
}

// Issue one 6 KB chunk (6x global_load_lds_dwordx4: 1 KB each, linear dest).
__device__ __forceinline__ void issue_chunk(const float* __restrict__ rowbase,
                                            int i, char* buf, int lane) {
  #pragma unroll
  for (int ch = 0; ch < 3; ++ch)
    #pragma unroll
    for (int h = 0; h < 2; ++h) {
      const float* g = rowbase + ch * 262144 + i * 512 + h * 256 + lane * 4;
      void* l = (void*)(buf + ch * 2048 + h * 1024);
      __builtin_amdgcn_global_load_lds(
          (const __attribute__((address_space(1))) void*)g,
          (__attribute__((address_space(3))) void*)l, 16, 0, 0);
    }
}

__global__ __launch_bounds__(64, 2)   // 1 wave/block; <=256 VGPR; 8 blocks/CU
void dct_mlp_fused(const float* __restrict__ x,
                   const u16* __restrict__ wf,
                   const float* __restrict__ b1,
                   const float* __restrict__ b2,
                   float* __restrict__ out) {
  __shared__ __align__(16) char smem[SMEM_BYTES];

  const int lane = threadIdx.x;     // lane == patch index within the tile
  const int quad = lane >> 4;
  const int l16  = lane & 15;

  const int tile = blockIdx.x;      // 0..2047
  const int gy   = tile & 63;
  const int b    = tile >> 6;

  char* pixA = smem + PIXA_OFF;
  char* pixB = smem + PIXB_OFF;
  const float* rowbase = x + (size_t)(b * 3) * 262144 + (size_t)(gy * 8) * 512;

  // ---- prologue: chunks 0,1 in flight (12 loads) ----
  issue_chunk(rowbase, 0, pixA, lane);
  issue_chunk(rowbase, 1, pixB, lane);

  const float D4[4][8] = {
    { 0.35355339f, 0.35355339f, 0.35355339f, 0.35355339f,
      0.35355339f, 0.35355339f, 0.35355339f, 0.35355339f},
    { 0.49039264f, 0.41573481f, 0.27778512f, 0.09754516f,
     -0.09754516f,-0.27778512f,-0.41573481f,-0.49039264f},
    { 0.46193977f, 0.19134172f,-0.19134172f,-0.46193977f,
     -0.46193977f,-0.19134172f, 0.19134172f, 0.46193977f},
    { 0.41573481f,-0.09754516f,-0.49039264f,-0.27778512f,
      0.27778512f, 0.49039264f, 0.09754516f,-0.41573481f}
  };

  float tmp[4][8];
  #pragma unroll
  for (int kr = 0; kr < 4; ++kr)
    #pragma unroll
    for (int c = 0; c < 8; ++c) tmp[kr][c] = 0.f;

  // ---- chunk pipeline: wait vmcnt(6) -> ds_read -> issue i+2 -> compute ----
  #pragma unroll
  for (int i = 0; i < 8; ++i) {
    char* buf = (i & 1) ? pixB : pixA;
    if (i < 7) { WAITVM(6); } else { WAITVM(0); }

    float4 rr[6];
    #pragma unroll
    for (int ch = 0; ch < 3; ++ch) {
      const char* base = buf + ch * 2048 + lane * 32;
      rr[ch * 2]     = *(const float4*)(base);
      rr[ch * 2 + 1] = *(const float4*)(base + 16);
    }
    __builtin_amdgcn_sched_barrier(0);   // pin reads before the overwrite issue
    if (i < 6) issue_chunk(rowbase, i + 2, buf, lane);

    float gr[8];
    gr[0] = 0.299f * rr[0].x + 0.587f * rr[2].x + 0.114f * rr[4].x;
    gr[1] = 0.299f * rr[0].y + 0.587f * rr[2].y + 0.114f * rr[4].y;
    gr[2] = 0.299f * rr[0].z + 0.587f * rr[2].z + 0.114f * rr[4].z;
    gr[3] = 0.299f * rr[0].w + 0.587f * rr[2].w + 0.114f * rr[4].w;
    gr[4] = 0.299f * rr[1].x + 0.587f * rr[3].x + 0.114f * rr[5].x;
    gr[5] = 0.299f * rr[1].y + 0.587f * rr[3].y + 0.114f * rr[5].y;
    gr[6] = 0.299f * rr[1].z + 0.587f * rr[3].z + 0.114f * rr[5].z;
    gr[7] = 0.299f * rr[1].w + 0.587f * rr[3].w + 0.114f * rr[5].w;
    #pragma unroll
    for (int kr = 0; kr < 4; ++kr)
      #pragma unroll
      for (int c = 0; c < 8; ++c)
        tmp[kr][c] = fmaf(D4[kr][i], gr[c], tmp[kr][c]);
  }

  // ---- col pass + write feats (16 coeffs) to LDS scratch ----
  char* featWw = smem + FEATW_OFF;
  #pragma unroll
  for (int kr = 0; kr < 4; ++kr) {
    float cc[4] = {0.f, 0.f, 0.f, 0.f};
    #pragma unroll
    for (int l = 0; l < 4; ++l)
      #pragma unroll
      for (int j = 0; j < 8; ++j)
        cc[l] = fmaf(tmp[kr][j], D4[l][j], cc[l]);
    ushort4 fv;
    fv.x = f2bf(cc[0]); fv.y = f2bf(cc[1]); fv.z = f2bf(cc[2]); fv.w = f2bf(cc[3]);
    *(ushort4*)(featWw + lane * 32 + kr * 8) = fv;
  }

  // feats B-fragments (kc-invariant): B[k=quad*8+j][p=l16], k>=16 zero.
  frag8 fB[4];
  #pragma unroll
  for (int pt = 0; pt < 4; ++pt) {
    frag8 z = {0,0,0,0,0,0,0,0};
    if (quad < 2)
      z = *(const frag8*)(featWw + (pt * 16 + l16) * 32 + quad * 16);
    fB[pt] = z;
  }

  // All remaining vmem is AFTER the final vmcnt(0) fence above (cannot hoist
  // across the "memory"-clobber asm) -> chunk counting stayed exact.
  float b2e[4];
  #pragma unroll
  for (int et = 0; et < 4; ++et) b2e[et] = b2[et * 16 + l16];

  f32x4 accs[4][4];
  #pragma unroll
  for (int pt = 0; pt < 4; ++pt)
    #pragma unroll
    for (int et = 0; et < 4; ++et) {
      f32x4 a = {b2e[et], b2e[et], b2e[et], b2e[et]};
      accs[pt][et] = a;
    }

  char* hWw = smem + HW_OFF;
  const unsigned hswz = (unsigned)((l16 & 3) << 4);   // p&3 == l16&3

  const u16* w1f = wf;          // frag8 per (nt, lane): nt*512 + lane*8 u16
  const u16* w2f = wf + 8192;   // frag8 per (kc*4+et, lane)

  // ---- MLP with ping-pong weight-frag prefetch (static idx, full unroll) ---
  frag8 pa0[2], pa1[2], pb[2][4];
  pa0[0] = *(const frag8*)(w1f + (size_t)0 * 512 + lane * 8);
  pa1[0] = *(const frag8*)(w1f + (size_t)1 * 512 + lane * 8);
  #pragma unroll
  for (int et = 0; et < 4; ++et)
    pb[0][et] = *(const frag8*)(w2f + (size_t)et * 512 + lane * 8);

  #pragma unroll
  for (int kc = 0; kc < 8; ++kc) {
    const int cur = kc & 1, nxt = cur ^ 1;
    if (kc < 7) {
      pa0[nxt] = *(const frag8*)(w1f + (size_t)(2 * kc + 2) * 512 + lane * 8);
      pa1[nxt] = *(const frag8*)(w1f + (size_t)(2 * kc + 3) * 512 + lane * 8);
      #pragma unroll
      for (int et = 0; et < 4; ++et)
        pb[nxt][et] = *(const frag8*)(w2f + (size_t)((kc + 1) * 4 + et) * 512 + lane * 8);
    }

    // ---- GEMM1: h chunk (32 hidden) = W1^T @ feats^T + b1, relu ----
    f32x4 g1[2][4];
    #pragma unroll
    for (int ntl = 0; ntl < 2; ++ntl) {
      float4 bb = *(const float4*)(b1 + kc * 32 + ntl * 16 + quad * 4);
      #pragma unroll
      for (int pt = 0; pt < 4; ++pt) {
        f32x4 ac = {bb.x, bb.y, bb.z, bb.w};
        g1[ntl][pt] = __builtin_amdgcn_mfma_f32_16x16x32_bf16(
            ntl ? pa1[cur] : pa0[cur], fB[pt], ac, 0, 0, 0);
      }
    }
    // relu + pack -> hW (swizzled)
    #pragma unroll
    for (int pt = 0; pt < 4; ++pt) {
      const unsigned rb = (unsigned)((pt * 16 + l16) * 64);
      #pragma unroll
      for (int ntl = 0; ntl < 2; ++ntl) {
        f32x4 v = g1[ntl][pt];
        float m0 = fmaxf(v[0], 0.f), m1 = fmaxf(v[1], 0.f);
        float m2 = fmaxf(v[2], 0.f), m3 = fmaxf(v[3], 0.f);
        unsigned d0, d1;
        asm("v_cvt_pk_bf16_f32 %0, %1, %2" : "=v"(d0) : "v"(m0), "v"(m1));
        asm("v_cvt_pk_bf16_f32 %0, %1, %2" : "=v"(d1) : "v"(m2), "v"(m3));
        uint2 dd; dd.x = d0; dd.y = d1;
        *(uint2*)(hWw + ((rb + ntl * 32 + quad * 8) ^ hswz)) = dd;
      }
    }
    // ---- GEMM2: emb += h_chunk @ W2[kc*32 .. kc*32+31][:] ----
    frag8 hA[4];
    #pragma unroll
    for (int pt = 0; pt < 4; ++pt) {
      const unsigned rb = (unsigned)((pt * 16 + l16) * 64);
      hA[pt] = *(const frag8*)(hWw + ((rb + quad * 16) ^ hswz));
    }
    #pragma unroll
    for (int pt = 0; pt < 4; ++pt)
      #pragma unroll
      for (int et = 0; et < 4; ++et)
        accs[pt][et] = __builtin_amdgcn_mfma_f32_16x16x32_bf16(
            hA[pt], pb[cur][et], accs[pt][et], 0, 0, 0);
  }

  // ======== Epilogue: direct store (lane regs j=0..3 are contiguous p) ======
  #pragma unroll
  for (int pt = 0; pt < 4; ++pt)
    #pragma unroll
    for (int et = 0; et < 4; ++et) {
      f32x4 v = accs[pt][et];
      float4 o; o.x = v[0]; o.y = v[1]; o.z = v[2]; o.w = v[3];
      float* dst = out + (((size_t)b * 64 + et * 16 + l16) * 64 + gy) * 64
                       + pt * 16 + quad * 4;
      *(float4*)dst = o;
    }
}

extern "C" void kernel_launch(void* const* d_in, const int* in_sizes, int n_in,
                              void* d_out, int out_size, void* d_ws, size_t ws_size,
                              hipStream_t stream) {
  const float* x  = (const float*)d_in[0];
  const float* W1 = (const float*)d_in[1];
  const float* b1 = (const float*)d_in[2];
  const float* W2 = (const float*)d_in[3];
  const float* b2 = (const float*)d_in[4];
  float* out = (float*)d_out;
  u16* wf = (u16*)d_ws;   // needs 48 KB of workspace

  prep_weights<<<dim3(12, 1, 1), dim3(256, 1, 1), 0, stream>>>(W1, W2, wf);
  dct_mlp_fused<<<dim3(2048, 1, 1), dim3(64, 1, 1), 0, stream>>>(x, wf, b1, b2, out);
}